// Round 6
// baseline (355.727 us; speedup 1.0000x reference)
//
#include <hip/hip_runtime.h>
#include <stdint.h>

// iSTFT as fused bf16-MFMA GEMM + overlap-add.
//   frames[m][n] = win[n] * sum_k X[m][k] * Tb'[k][n]          (n in [0,512))
//   X[m=(b,t)][k=2f+c] = transform[b,f,t,c]   (K = 514, padded to 544)
//   Tb'[2f+0][n] =  s_f*cos(2*pi*f*n/512)/512   (NO window folded)
//   Tb'[2f+1][n] = -s_f*sin(2*pi*f*n/512)/512,  s_f = (f==0||f==256)?1:2
// R6 half-table trick: Tb'[k][n+256] = (-1)^f * Tb'[k][n]  ->  table is only
// N=256 cols; right half uses A with (-1)^f folded in (XOR of 2 dwords/frag).
// Halves B L2 traffic (R5 diagnosis: 570MB B re-fetch ~ 74% of L2 BW -> queue
// latency) and halves B LDS reads. A now loads DIRECT global->reg (drops sA:
// R4 counters proved all 2.79M bank-conflict cycles were the A-path; B reads
// and epilogue are conflict-free). Pipeline: single raw s_barrier per K-step,
// A depth-2 (q[2][8] ping-pong), B depth-2 (4 x 16KB LDS buffers), uniform
// s_waitcnt vmcnt(10) (A(t+1)8 + B(t+1)2 stay in flight; never drains).
// Window applied in epilogue (f32) before bf16 staging; OLA unchanged.

#define EPS_F 1.1920928955078125e-07f
#define TWO_PI_OVER_512 1.2271846303085130e-02f

typedef __bf16 bf16x8 __attribute__((ext_vector_type(8)));
typedef float f32x4 __attribute__((ext_vector_type(4)));
typedef uint32_t u32x4 __attribute__((ext_vector_type(4)));

__device__ __forceinline__ uint16_t f2bf_bits(float x) {
  return __builtin_bit_cast(uint16_t, (__bf16)x);
}
__device__ __forceinline__ float bf2f_bits(uint16_t u) {
  return (float)__builtin_bit_cast(__bf16, u);
}

#define GLOAD16(srcp, dstp)                                                   \
  __builtin_amdgcn_global_load_lds(                                          \
      (const __attribute__((address_space(1))) uint32_t*)(srcp),             \
      (__attribute__((address_space(3))) uint32_t*)(dstp), 16, 0, 0)

// Half-table: K=544 rows x N=256, bf16, packed 16B fragment units:
//   unit u = (k>>3)*256 + n ; byte = (u<<4 ^ ((g&3)<<5)) + (k&7)*2
// XOR = LDS bank swizzle baked into global layout (tile copies verbatim).
__global__ void build_table_kernel(uint8_t* __restrict__ tb) {
  const int k = blockIdx.x;        // 0..543
  const int g = k >> 3;
  const int n = threadIdx.x;       // 0..255
  float v = 0.0f;
  if (k < 514) {
    const int f = k >> 1;
    const float s = (f == 0 || f == 256) ? 1.0f : 2.0f;
    const int a = (f * n) & 511;   // exact angle reduction
    const float th = (float)a * TWO_PI_OVER_512;
    const float tr = (k & 1) ? -sinf(th) : cosf(th);
    v = s * tr * (1.0f / 512.0f);
  }
  const int off = (((g * 256 + n) << 4) ^ ((g & 3) << 5)) + ((k & 7) << 1);
  *(uint16_t*)(tb + off) = f2bf_bits(v);
}

// epilogue frame buffer: 512 cols x 32 rows bf16, pitch 72B, swizzled
__device__ __forceinline__ float rd_sf(const uint8_t* sF, int col, int row2) {
  return bf2f_bits(*(const uint16_t*)(
      sF + col * 72 + ((row2 * 2) ^ (((col >> 4) & 3) << 2))));
}

// One block: batch b, 64 consecutive frames [t0, t0+64), full N=512.
// Owns output chunks [t0+1, t0+63] (+ chunk 0 / chunk 4000 at the ends).
__global__ __launch_bounds__(512, 4)
void istft_fused_kernel(const float2* __restrict__ in,   // [B*257*4000] (re,im)
                        const float* __restrict__ win,   // [512]
                        const uint8_t* __restrict__ tb,  // packed half-table
                        float* __restrict__ out) {
  __shared__ __align__(1024) uint8_t smem[65536];
  uint8_t* sB = smem;   // 4 x 16KB B buffers
  uint8_t* sF = smem;   // epilogue alias: 512 cols x 72B

  const int tid  = threadIdx.x;
  const int lane = tid & 63;
  const int wave = tid >> 6;       // 0..7
  const int wn   = wave & 3;       // N-quarter (of 256)
  const int wm   = wave >> 2;      // M-half
  const int l15  = lane & 15;
  const int g    = lane >> 4;      // k-group within fragment
  const int b  = blockIdx.y;
  const int ib = blockIdx.x;       // 0..63
  const int t0 = (ib == 63) ? 3936 : ib * 63;

  f32x4 accL[2][4], accR[2][4];
#pragma unroll
  for (int mi = 0; mi < 2; ++mi)
#pragma unroll
    for (int nj = 0; nj < 4; ++nj) {
      accL[mi][nj] = (f32x4){0.f, 0.f, 0.f, 0.f};
      accR[mi][nj] = (f32x4){0.f, 0.f, 0.f, 0.f};
    }

  const long inBase = (long)b * (257L * 4000);
  const long tARow  = inBase + (t0 + wm * 32 + l15);  // + mi*16 + f*4000

  float2 q[2][8];  // A ping-pong: q[ks&1][mi*4+p]

  // issue the 8 A-loads of K-step ks (uniform count; ks=16 loads f=256 row)
  auto issueA = [&](const int ks) {
    float2* qd = q[ks & 1];
    if (ks < 16) {
#pragma unroll
      for (int mi = 0; mi < 2; ++mi)
#pragma unroll
        for (int p = 0; p < 4; ++p) {
          const int f = ks * 16 + g * 4 + p;   // <= 255 for ks<=15
          qd[mi * 4 + p] = in[tARow + mi * 16 + (long)f * 4000];
        }
    } else {
#pragma unroll
      for (int mi = 0; mi < 2; ++mi)
#pragma unroll
        for (int p = 0; p < 4; ++p)
          qd[mi * 4 + p] = in[tARow + mi * 16 + 256L * 4000];
    }
  };
  // issue the 2 B global_load_lds of K-step t into buf[t&3]
  auto issueB = [&](const int t) {
    const uint8_t* src = tb + t * 16384 + wave * 2048 + lane * 16;
    uint8_t* dst = sB + (t & 3) * 16384 + wave * 2048 + lane * 16;
    GLOAD16(src, dst);
    GLOAD16(src + 1024, dst + 1024);
  };

  // ---- prologue: A0(8), B0(2), A1(8), B1(2)  (order = vmcnt contract) ----
  issueA(0);
  __builtin_amdgcn_sched_barrier(0);
  issueB(0);
  __builtin_amdgcn_sched_barrier(0);
  issueA(1);
  __builtin_amdgcn_sched_barrier(0);
  issueB(1);
  __builtin_amdgcn_sched_barrier(0);

#pragma unroll
  for (int ks = 0; ks < 17; ++ks) {
    // wait: retire through {A(ks), B(ks)}; keep A(ks+1),B(ks+1) in flight
    if (ks < 16)
      asm volatile("s_waitcnt vmcnt(10)" ::: "memory");
    else
      asm volatile("s_waitcnt vmcnt(0)" ::: "memory");
    __builtin_amdgcn_s_barrier();   // buf[ks&3] published to all waves
    __builtin_amdgcn_sched_barrier(0);

    // ---- A fragments from q[ks&1]; afx = af with (-1)^f folded ----
    bf16x8 af[2], afx[2];
#pragma unroll
    for (int mi = 0; mi < 2; ++mi) {
      bf16x8 a;
#pragma unroll
      for (int p = 0; p < 4; ++p) {
        float2 v = q[ks & 1][mi * 4 + p];
        if (ks == 16 && !(g == 0 && p == 0)) { v.x = 0.f; v.y = 0.f; }
        a[2 * p]     = (__bf16)v.x;   // k = g*8 + 2p   (re)
        a[2 * p + 1] = (__bf16)v.y;   // k = g*8 + 2p+1 (im)
      }
      af[mi] = a;
      u32x4 u = __builtin_bit_cast(u32x4, a);  // dwords = f-offsets 0..3
      u[1] ^= 0x80008000u;                     // (-1)^f: negate odd f
      u[3] ^= 0x80008000u;
      afx[mi] = __builtin_bit_cast(bf16x8, u);
    }

    // ---- refill pipeline: A(ks+2) into q[ks&1] (regs just consumed),
    //      then B(ks+2) into buf[(ks+2)&3] (read ks steps ago; 2 barriers) --
    if (ks < 15) {
      issueA(ks + 2);
      __builtin_amdgcn_sched_barrier(0);
      issueB(ks + 2);
      __builtin_amdgcn_sched_barrier(0);
    }

    // ---- B fragments from LDS + 16 MFMA ----
    const uint8_t* sBc = sB + (ks & 3) * 16384;
    const int nbase = ((g * 256 + wn * 64 + l15) << 4) ^ (g << 5);
#pragma unroll
    for (int nj = 0; nj < 4; ++nj) {
      const bf16x8 bfr = *(const bf16x8*)(sBc + nbase + (nj << 8));
      accL[0][nj] = __builtin_amdgcn_mfma_f32_16x16x32_bf16(af[0],  bfr, accL[0][nj], 0, 0, 0);
      accR[0][nj] = __builtin_amdgcn_mfma_f32_16x16x32_bf16(afx[0], bfr, accR[0][nj], 0, 0, 0);
      accL[1][nj] = __builtin_amdgcn_mfma_f32_16x16x32_bf16(af[1],  bfr, accL[1][nj], 0, 0, 0);
      accR[1][nj] = __builtin_amdgcn_mfma_f32_16x16x32_bf16(afx[1], bfr, accR[1][nj], 0, 0, 0);
    }
  }

  // ---- epilogue: two 32-frame passes through the 36KB swizzled buffer ----
  __syncthreads();  // all K-loop LDS reads done; smem becomes sF
  float* outb = out + (long)b * 1024256;
  const float invd = 1.0f / (1.0f + EPS_F);

  float wL[4], wR[4];
#pragma unroll
  for (int nj = 0; nj < 4; ++nj) {
    wL[nj] = win[wn * 64 + nj * 16 + l15];
    wR[nj] = win[wn * 64 + nj * 16 + l15 + 256];
  }

#define STAGE_PASS()                                                          \
  {                                                                           \
    _Pragma("unroll")                                                         \
    for (int mi = 0; mi < 2; ++mi) {                                          \
      const int q4 = mi * 16 + (g << 2); /* D row=(lane>>4)*4+r */            \
      _Pragma("unroll")                                                       \
      for (int nj = 0; nj < 4; ++nj) {                                        \
        const int colL = wn * 64 + nj * 16 + l15;                             \
        const int colR = colL + 256;                                          \
        const int swzL = ((colL >> 4) & 3) << 2;                              \
        const int swzR = ((colR >> 4) & 3) << 2;                              \
        const f32x4 aL = accL[mi][nj];                                        \
        const f32x4 aR = accR[mi][nj];                                        \
        const float wl = wL[nj], wr = wR[nj];                                 \
        uint32_t lo = (uint32_t)f2bf_bits(aL[0] * wl) |                       \
                      ((uint32_t)f2bf_bits(aL[1] * wl) << 16);                \
        uint32_t hi = (uint32_t)f2bf_bits(aL[2] * wl) |                       \
                      ((uint32_t)f2bf_bits(aL[3] * wl) << 16);                \
        *(uint32_t*)(sF + colL * 72 + ((q4 * 2) ^ swzL))       = lo;          \
        *(uint32_t*)(sF + colL * 72 + (((q4 + 2) * 2) ^ swzL)) = hi;          \
        lo = (uint32_t)f2bf_bits(aR[0] * wr) |                                \
             ((uint32_t)f2bf_bits(aR[1] * wr) << 16);                         \
        hi = (uint32_t)f2bf_bits(aR[2] * wr) |                                \
             ((uint32_t)f2bf_bits(aR[3] * wr) << 16);                         \
        *(uint32_t*)(sF + colR * 72 + ((q4 * 2) ^ swzR))       = lo;          \
        *(uint32_t*)(sF + colR * 72 + (((q4 + 2) * 2) ^ swzR)) = hi;          \
      }                                                                       \
    }                                                                         \
  }

  // stage group 0 (frames 0..31 = waves wm==0)
  if (wm == 0) STAGE_PASS();
  __syncthreads();
  // OLA chunks 1..31 (frames cl-1, cl both in group 0)
#pragma unroll 1
  for (int i = tid; i < 31 * 256; i += 512) {
    const int cl = 1 + (i >> 8);
    const int r  = i & 255;
    const float v0 = rd_sf(sF, 256 + r, cl - 1);
    const float v1 = rd_sf(sF, r, cl);
    outb[(t0 + cl) * 256 + r] = (v0 + v1) * invd;
  }
  if (ib == 0 && tid < 256) {  // chunk 0: only frame 0, n=r, denorm=win[r]^2
    const float w = win[tid];
    outb[tid] = rd_sf(sF, tid, 0) / (w * w + EPS_F);
  }
  // carry frame 31's upper half for the straddling chunk 32
  const float vsave = (tid < 256) ? rd_sf(sF, 256 + tid, 31) : 0.0f;
  __syncthreads();
  // stage group 1 (frames 32..63 = waves wm==1)
  if (wm == 1) STAGE_PASS();
  __syncthreads();
  if (tid < 256)  // chunk 32: frame 31 (saved) + frame 32 (row2=0)
    outb[(t0 + 32) * 256 + tid] = (vsave + rd_sf(sF, tid, 0)) * invd;
  // OLA chunks 33..63 (frames cl-1, cl in group 1; row2 = frame - 32)
#pragma unroll 1
  for (int i = tid; i < 31 * 256; i += 512) {
    const int cl = 33 + (i >> 8);
    const int r  = i & 255;
    const float v0 = rd_sf(sF, 256 + r, cl - 33);
    const float v1 = rd_sf(sF, r, cl - 32);
    outb[(t0 + cl) * 256 + r] = (v0 + v1) * invd;
  }
  if (ib == 63 && tid < 256) {  // chunk 4000: only frame 3999, n=256+r
    const float w = win[256 + tid];
    outb[1024000 + tid] = rd_sf(sF, 256 + tid, 31) / (w * w + EPS_F);
  }
}

extern "C" void kernel_launch(void* const* d_in, const int* in_sizes, int n_in,
                              void* d_out, int out_size, void* d_ws, size_t ws_size,
                              hipStream_t stream) {
  (void)in_sizes; (void)n_in; (void)out_size; (void)ws_size;
  const float2* tr = (const float2*)d_in[0];
  const float* win = (const float*)d_in[1];
  uint8_t* tb = (uint8_t*)d_ws;  // 544/8 * 256 * 16 = 278528 bytes
  build_table_kernel<<<dim3(544), dim3(256), 0, stream>>>(tb);
  istft_fused_kernel<<<dim3(64, 16), dim3(512), 0, stream>>>(tr, win, tb,
                                                             (float*)d_out);
}

// Round 7
// 68.342 us; speedup vs baseline: 5.2051x; 5.2051x over previous
//
#include <hip/hip_runtime.h>
#include <stdint.h>

// iSTFT as fused bf16-MFMA GEMM + overlap-add, with even/odd frequency fold.
//   frames[m][n]     = win[n]     * (E[m][n] + O[m][n])      n in [0,256)
//   frames[m][n+256] = win[n+256] * (E[m][n] - O[m][n])
//   E = sum over even f (K=258, 9 steps), O = sum over odd f (K=256, 8 steps)
// since T[f][n+256] = (-1)^f T[f][n]. This HALVES the GEMM FLOPs vs R5 and
// halves B traffic; R6's mistake (same-K duplicate accumulate -> 145 live regs
// -> scratch spill, WRITE_SIZE 687MB) is avoided: one af per step, 8 MFMA.
// A loads DIRECT global->reg depth-2 ping-pong (no sA: R4/R6 proved all bank
// conflicts were the A-LDS path). B: global_load_lds into 4x16KB buffers,
// depth-2. One raw s_barrier per K-step, uniform s_waitcnt vmcnt(10)
// (A(t+1)8+B(t+1)2 always in flight; never drains in the loop).
// Register budget (launch_bounds(512,4) -> 128 cap): acc 64 + q 32 + af 8
// + addressing ~15 = ~119. Watch WRITE_SIZE for spill.

#define EPS_F 1.1920928955078125e-07f
#define TWO_PI_OVER_512 1.2271846303085130e-02f

typedef __bf16 bf16x8 __attribute__((ext_vector_type(8)));
typedef float f32x4 __attribute__((ext_vector_type(4)));

__device__ __forceinline__ uint16_t f2bf_bits(float x) {
  return __builtin_bit_cast(uint16_t, (__bf16)x);
}
__device__ __forceinline__ float bf2f_bits(uint16_t u) {
  return (float)__builtin_bit_cast(__bf16, u);
}

#define GLOAD16(srcp, dstp)                                                   \
  __builtin_amdgcn_global_load_lds(                                          \
      (const __attribute__((address_space(1))) uint32_t*)(srcp),             \
      (__attribute__((address_space(3))) uint32_t*)(dstp), 16, 0, 0)

// Table: 544 rows x N=256 bf16. Rows 0..287 = even-f phase (k_e = 2*fe+c,
// f = 2*fe, fe<=128 valid, rest zero-pad); rows 288..543 = odd-f phase
// (k_o = 2*fo+c, f = 2*fo+1). Packed 16B units: unit u = (k>>3)*256 + n,
// byte = (u<<4 ^ ((g&3)<<5)) + (k&7)*2  (bank swizzle baked into global
// layout so global_load_lds tile copies are verbatim).
__global__ void build_table_kernel(uint8_t* __restrict__ tb) {
  const int k = blockIdx.x;        // 0..543
  const int g = k >> 3;
  const int n = threadIdx.x;       // 0..255
  float v = 0.0f;
  int f, c, valid;
  if (k < 288) {
    const int fe = k >> 1;
    c = k & 1; f = 2 * fe; valid = (fe <= 128);
  } else {
    const int ko = k - 288;
    c = ko & 1; f = 2 * (ko >> 1) + 1; valid = 1;
  }
  if (valid) {
    const float s = (f == 0 || f == 256) ? 1.0f : 2.0f;
    const int a = (f * n) & 511;   // exact angle reduction
    const float th = (float)a * TWO_PI_OVER_512;
    const float tr = c ? -sinf(th) : cosf(th);
    v = s * tr * (1.0f / 512.0f);
  }
  const int off = (((g * 256 + n) << 4) ^ ((g & 3) << 5)) + ((k & 7) << 1);
  *(uint16_t*)(tb + off) = f2bf_bits(v);
}

// epilogue frame buffer: 512 cols x 32 rows bf16, pitch 72B, swizzled
__device__ __forceinline__ float rd_sf(const uint8_t* sF, int col, int row2) {
  return bf2f_bits(*(const uint16_t*)(
      sF + col * 72 + ((row2 * 2) ^ (((col >> 4) & 3) << 2))));
}

// One block: batch b, 64 consecutive frames [t0, t0+64), full N=512.
// Owns output chunks [t0+1, t0+63] (+ chunk 0 / chunk 4000 at the ends).
__global__ __launch_bounds__(512, 4)
void istft_fused_kernel(const float2* __restrict__ in,   // [B*257*4000] (re,im)
                        const float* __restrict__ win,   // [512]
                        const uint8_t* __restrict__ tb,  // packed table
                        float* __restrict__ out) {
  __shared__ __align__(1024) uint8_t smem[65536];
  uint8_t* sB = smem;   // 4 x 16KB B buffers
  uint8_t* sF = smem;   // epilogue alias: 512 cols x 72B

  const int tid  = threadIdx.x;
  const int lane = tid & 63;
  const int wave = tid >> 6;       // 0..7
  const int wn   = wave & 3;       // N-quarter of the folded 256
  const int wm   = wave >> 2;      // M-half
  const int l15  = lane & 15;
  const int g    = lane >> 4;      // k-group within fragment
  const int b  = blockIdx.y;
  const int ib = blockIdx.x;       // 0..63
  const int t0 = (ib == 63) ? 3936 : ib * 63;

  f32x4 accE[2][4], accO[2][4];
#pragma unroll
  for (int mi = 0; mi < 2; ++mi)
#pragma unroll
    for (int nj = 0; nj < 4; ++nj) {
      accE[mi][nj] = (f32x4){0.f, 0.f, 0.f, 0.f};
      accO[mi][nj] = (f32x4){0.f, 0.f, 0.f, 0.f};
    }

  const long inBase = (long)b * (257L * 4000);
  const long tARow  = inBase + (t0 + wm * 32 + l15);  // + mi*16 + f*4000

  float2 q[2][8];  // A ping-pong: q[ks&1][mi*4+p]

  // step KS (compile-time under full unroll):
  //   KS<9  even phase: fe = KS*16+g*4+p (clamp 128; B rows are 0 there)
  //   KS>=9 odd  phase: f = 2*((KS-9)*16+g*4+p)+1
#define ISSUE_A(KS)                                                           \
  {                                                                           \
    float2* qd = q[(KS) & 1];                                                 \
    _Pragma("unroll") for (int mi = 0; mi < 2; ++mi)                          \
    _Pragma("unroll") for (int p = 0; p < 4; ++p) {                           \
      int f;                                                                  \
      if ((KS) < 9) {                                                         \
        int fe = (KS) * 16 + g * 4 + p;                                       \
        if (fe > 128) fe = 128;                                               \
        f = 2 * fe;                                                           \
      } else {                                                                \
        f = 2 * (((KS) - 9) * 16 + g * 4 + p) + 1;                            \
      }                                                                       \
      qd[mi * 4 + p] = in[tARow + mi * 16 + (long)f * 4000];                  \
    }                                                                         \
  }
#define ISSUE_B(T)                                                            \
  {                                                                           \
    const uint8_t* src = tb + (T) * 16384 + wave * 2048 + lane * 16;          \
    uint8_t* dst = sB + ((T) & 3) * 16384 + wave * 2048 + lane * 16;          \
    GLOAD16(src, dst);                                                        \
    GLOAD16(src + 1024, dst + 1024);                                          \
  }
#define MFMA_STEP(ACC)                                                        \
  _Pragma("unroll") for (int nj = 0; nj < 4; ++nj) {                          \
    const bf16x8 bfr = *(const bf16x8*)(sBc + nbase + (nj << 8));             \
    ACC[0][nj] = __builtin_amdgcn_mfma_f32_16x16x32_bf16(af[0], bfr,          \
                                                         ACC[0][nj], 0, 0, 0);\
    ACC[1][nj] = __builtin_amdgcn_mfma_f32_16x16x32_bf16(af[1], bfr,          \
                                                         ACC[1][nj], 0, 0, 0);\
  }

  // ---- prologue: A0(8), B0(2), A1(8), B1(2) — order IS the vmcnt contract
  ISSUE_A(0);
  __builtin_amdgcn_sched_barrier(0);
  ISSUE_B(0);
  __builtin_amdgcn_sched_barrier(0);
  ISSUE_A(1);
  __builtin_amdgcn_sched_barrier(0);
  ISSUE_B(1);
  __builtin_amdgcn_sched_barrier(0);

  const int nbase = ((g * 256 + wn * 64 + l15) << 4) ^ (g << 5);

#pragma unroll
  for (int ks = 0; ks < 17; ++ks) {
    // retire through {A(ks),B(ks)}; keep A(ks+1),B(ks+1) in flight
    if (ks < 16)
      asm volatile("s_waitcnt vmcnt(10)" ::: "memory");
    else
      asm volatile("s_waitcnt vmcnt(0)" ::: "memory");
    __builtin_amdgcn_s_barrier();   // buf[ks&3] published to all waves
    __builtin_amdgcn_sched_barrier(0);

    // ---- A fragments from q[ks&1] (k_local = g*8 + 2p + c) ----
    bf16x8 af[2];
#pragma unroll
    for (int mi = 0; mi < 2; ++mi) {
      bf16x8 a;
#pragma unroll
      for (int p = 0; p < 4; ++p) {
        const float2 v = q[ks & 1][mi * 4 + p];
        a[2 * p]     = (__bf16)v.x;
        a[2 * p + 1] = (__bf16)v.y;
      }
      af[mi] = a;
    }

    // ---- refill: A(ks+2) into q[ks&1] (just consumed), B(ks+2) ----
    if (ks < 15) {
      ISSUE_A(ks + 2);
      __builtin_amdgcn_sched_barrier(0);
      ISSUE_B(ks + 2);
      __builtin_amdgcn_sched_barrier(0);
    }

    // ---- B fragments from LDS + 8 MFMA into phase accumulator ----
    const uint8_t* sBc = sB + (ks & 3) * 16384;
    if (ks < 9) {
      MFMA_STEP(accE);
    } else {
      MFMA_STEP(accO);
    }
  }

  // ---- epilogue: two 32-frame passes through the 36KB swizzled buffer ----
  __syncthreads();  // all K-loop LDS reads done; smem becomes sF
  float* outb = out + (long)b * 1024256;
  const float invd = 1.0f / (1.0f + EPS_F);

  float wL[4], wR[4];
#pragma unroll
  for (int nj = 0; nj < 4; ++nj) {
    wL[nj] = win[wn * 64 + nj * 16 + l15];
    wR[nj] = win[wn * 64 + nj * 16 + l15 + 256];
  }

#define STAGE_PASS()                                                          \
  {                                                                           \
    _Pragma("unroll")                                                         \
    for (int mi = 0; mi < 2; ++mi) {                                          \
      const int q4 = mi * 16 + (g << 2); /* D row=(lane>>4)*4+r */            \
      _Pragma("unroll")                                                       \
      for (int nj = 0; nj < 4; ++nj) {                                        \
        const int colL = wn * 64 + nj * 16 + l15;                             \
        const int colR = colL + 256;                                          \
        const int swzL = ((colL >> 4) & 3) << 2;                              \
        const int swzR = ((colR >> 4) & 3) << 2;                              \
        const f32x4 e = accE[mi][nj];                                         \
        const f32x4 o = accO[mi][nj];                                         \
        const float wl = wL[nj], wr = wR[nj];                                 \
        uint32_t lo = (uint32_t)f2bf_bits((e[0] + o[0]) * wl) |               \
                      ((uint32_t)f2bf_bits((e[1] + o[1]) * wl) << 16);        \
        uint32_t hi = (uint32_t)f2bf_bits((e[2] + o[2]) * wl) |               \
                      ((uint32_t)f2bf_bits((e[3] + o[3]) * wl) << 16);        \
        *(uint32_t*)(sF + colL * 72 + ((q4 * 2) ^ swzL))       = lo;          \
        *(uint32_t*)(sF + colL * 72 + (((q4 + 2) * 2) ^ swzL)) = hi;          \
        lo = (uint32_t)f2bf_bits((e[0] - o[0]) * wr) |                        \
             ((uint32_t)f2bf_bits((e[1] - o[1]) * wr) << 16);                 \
        hi = (uint32_t)f2bf_bits((e[2] - o[2]) * wr) |                        \
             ((uint32_t)f2bf_bits((e[3] - o[3]) * wr) << 16);                 \
        *(uint32_t*)(sF + colR * 72 + ((q4 * 2) ^ swzR))       = lo;          \
        *(uint32_t*)(sF + colR * 72 + (((q4 + 2) * 2) ^ swzR)) = hi;          \
      }                                                                       \
    }                                                                         \
  }

  // stage group 0 (frames 0..31 = waves wm==0)
  if (wm == 0) STAGE_PASS();
  __syncthreads();
  // OLA chunks 1..31 (frames cl-1, cl both in group 0)
#pragma unroll 1
  for (int i = tid; i < 31 * 256; i += 512) {
    const int cl = 1 + (i >> 8);
    const int r  = i & 255;
    const float v0 = rd_sf(sF, 256 + r, cl - 1);
    const float v1 = rd_sf(sF, r, cl);
    outb[(t0 + cl) * 256 + r] = (v0 + v1) * invd;
  }
  if (ib == 0 && tid < 256) {  // chunk 0: only frame 0, n=r, denorm=win[r]^2
    const float w = win[tid];
    outb[tid] = rd_sf(sF, tid, 0) / (w * w + EPS_F);
  }
  // carry frame 31's upper half for the straddling chunk 32
  const float vsave = (tid < 256) ? rd_sf(sF, 256 + tid, 31) : 0.0f;
  __syncthreads();
  // stage group 1 (frames 32..63 = waves wm==1)
  if (wm == 1) STAGE_PASS();
  __syncthreads();
  if (tid < 256)  // chunk 32: frame 31 (saved) + frame 32 (row2=0)
    outb[(t0 + 32) * 256 + tid] = (vsave + rd_sf(sF, tid, 0)) * invd;
  // OLA chunks 33..63 (frames cl-1, cl in group 1; row2 = frame - 32)
#pragma unroll 1
  for (int i = tid; i < 31 * 256; i += 512) {
    const int cl = 33 + (i >> 8);
    const int r  = i & 255;
    const float v0 = rd_sf(sF, 256 + r, cl - 33);
    const float v1 = rd_sf(sF, r, cl - 32);
    outb[(t0 + cl) * 256 + r] = (v0 + v1) * invd;
  }
  if (ib == 63 && tid < 256) {  // chunk 4000: only frame 3999, n=256+r
    const float w = win[256 + tid];
    outb[1024000 + tid] = rd_sf(sF, 256 + tid, 31) / (w * w + EPS_F);
  }
}

extern "C" void kernel_launch(void* const* d_in, const int* in_sizes, int n_in,
                              void* d_out, int out_size, void* d_ws, size_t ws_size,
                              hipStream_t stream) {
  (void)in_sizes; (void)n_in; (void)out_size; (void)ws_size;
  const float2* tr = (const float2*)d_in[0];
  const float* win = (const float*)d_in[1];
  uint8_t* tb = (uint8_t*)d_ws;  // 544/8 * 256 * 16 = 278528 bytes
  build_table_kernel<<<dim3(544), dim3(256), 0, stream>>>(tb);
  istft_fused_kernel<<<dim3(64, 16), dim3(512), 0, stream>>>(tr, win, tb,
                                                             (float*)d_out);
}